// Round 1
// baseline (573.389 us; speedup 1.0000x reference)
//
#include <hip/hip_runtime.h>
#include <cstdint>
#include <cstddef>

#define S_LEN  256
#define BATCH  32
#define HID    256
#define EMB    256
#define TSTEPS 10

// ---------------------------------------------------------------------------
// Kernel 1: X1_all[(s*BATCH+b)][i] = b1[i] + (tok!=0) * dot(emb[tok,:], W1[i,:])
// delta1 is timestep-invariant within a word, so precompute for all 8192 pairs.
// Block = 256 threads (thread = neuron i), block handles 8 (s,b) pairs sharing
// one pass over W1 row i. Embedding rows are wave-uniform -> scalar (s_load)
// path via readfirstlane; padding_idx=0 handled by scaling the dot by 0.
// ---------------------------------------------------------------------------
__global__ __launch_bounds__(256) void x1_gemm_kernel(
    const int* __restrict__ text, const float* __restrict__ emb,
    const float* __restrict__ W1, const float* __restrict__ b1,
    float* __restrict__ X1)
{
    const int i  = threadIdx.x;       // neuron
    const int p0 = blockIdx.x * 8;    // (s,b) pair base

    const float4* __restrict__ wq = (const float4*)(W1 + (size_t)i * EMB);

    const float4* xq[8];
    float scale[8];
#pragma unroll
    for (int g = 0; g < 8; ++g) {
        int tok = text[p0 + g];
        tok = __builtin_amdgcn_readfirstlane(tok);   // force wave-uniform
        xq[g]    = (const float4*)(emb + (size_t)tok * EMB);
        scale[g] = (tok == 0) ? 0.0f : 1.0f;         // padding_idx = 0
    }

    float acc[8] = {0.f,0.f,0.f,0.f,0.f,0.f,0.f,0.f};
#pragma unroll 4
    for (int j4 = 0; j4 < EMB / 4; ++j4) {
        float4 w = wq[j4];
#pragma unroll
        for (int g = 0; g < 8; ++g) {
            float4 x = xq[g][j4];
            acc[g] += w.x * x.x + w.y * x.y + w.z * x.z + w.w * x.w;
        }
    }

    const float bi = b1[i];
#pragma unroll
    for (int g = 0; g < 8; ++g)
        X1[(size_t)(p0 + g) * HID + i] = bi + scale[g] * acc[g];
}

// ---------------------------------------------------------------------------
// Kernel 2: the sequential recurrence. One wave (64 lanes) per batch element,
// lane l owns neurons {l, l+64, l+128, l+192} for m1/m2/acc (registers only).
// Spike exchange: __ballot per 64-neuron group -> full 256-bit mask in sgprs,
// no barriers. s@W^T computed exactly as sum of active columns (iterate set
// bits; wave-uniform branch, empty when no spikes).
// ---------------------------------------------------------------------------
__global__ __launch_bounds__(64) void snn_seq_kernel(
    const int* __restrict__ text, const float* __restrict__ emb,
    const float* __restrict__ W1, const float* __restrict__ b1,
    const float* __restrict__ X1all, const int use_precomp,
    const float* __restrict__ W2, const float* __restrict__ b2,
    const float* __restrict__ W3, const float* __restrict__ b3,
    const float* __restrict__ thr1p, const float* __restrict__ leak1p,
    const float* __restrict__ thr2p, const float* __restrict__ leak2p,
    const float* __restrict__ Wa1, const float* __restrict__ ba1,
    const float* __restrict__ Wa2, const float* __restrict__ ba2,
    float* __restrict__ out)
{
    const int b = blockIdx.x;    // batch element
    const int l = threadIdx.x;   // lane

    const float thr1  = thr1p[0],  thr2  = thr2p[0];
    const float leak1 = leak1p[0], leak2 = leak2p[0];

    float m1[4]  = {0.f,0.f,0.f,0.f};
    float m2[4]  = {0.f,0.f,0.f,0.f};
    float acc[4] = {0.f,0.f,0.f,0.f};
    float b1v[4], b2v[4], b3v[4];
#pragma unroll
    for (int k = 0; k < 4; ++k) {
        b1v[k] = b1[l + 64 * k];
        b2v[k] = b2[l + 64 * k];
        b3v[k] = b3[l + 64 * k];
    }

    float X1c[4] = {0.f,0.f,0.f,0.f};
    float X1n[4] = {0.f,0.f,0.f,0.f};

    if (use_precomp) {
        const size_t base0 = ((size_t)0 * BATCH + b) * HID + l;
#pragma unroll
        for (int k = 0; k < 4; ++k) X1c[k] = X1all[base0 + 64 * k];
    }

    for (int s = 0; s < S_LEN; ++s) {
        if (use_precomp) {
            if (s + 1 < S_LEN) {   // prefetch next word's delta1 (hidden under t-loop)
                const size_t basen = ((size_t)(s + 1) * BATCH + b) * HID + l;
#pragma unroll
                for (int k = 0; k < 4; ++k) X1n[k] = X1all[basen + 64 * k];
            }
        } else {
            // fallback (small d_ws): compute delta1 in-kernel
            int tok = text[s * BATCH + b];
            tok = __builtin_amdgcn_readfirstlane(tok);
            const float4* __restrict__ xr = (const float4*)(emb + (size_t)tok * EMB);
            const float sc = (tok == 0) ? 0.0f : 1.0f;
#pragma unroll
            for (int k = 0; k < 4; ++k) {
                const float4* __restrict__ wr =
                    (const float4*)(W1 + (size_t)(l + 64 * k) * EMB);
                float a = 0.f;
                for (int j4 = 0; j4 < EMB / 4; ++j4) {
                    float4 w = wr[j4];
                    float4 x = xr[j4];
                    a += w.x * x.x + w.y * x.y + w.z * x.z + w.w * x.w;
                }
                X1c[k] = b1v[k] + sc * a;
            }
        }

#pragma unroll
        for (int t = 0; t < TSTEPS; ++t) {
            unsigned long long msk[4];

            // ---- LIF layer 1 (soft reset); spike iff mem > thr (thr>0) ----
#pragma unroll
            for (int k = 0; k < 4; ++k) {
                m1[k] = fmaf(m1[k], leak1, X1c[k]);
                const bool sp = m1[k] > thr1;
                msk[k] = __ballot(sp);
                m1[k] -= sp ? thr1 : 0.f;
            }

            // ---- delta2 = s1 @ W2^T + b2 : sum of active columns ----
            float d2[4] = {b2v[0], b2v[1], b2v[2], b2v[3]};
            if (msk[0] | msk[1] | msk[2] | msk[3]) {
#pragma unroll
                for (int k2 = 0; k2 < 4; ++k2) {
                    unsigned long long m = msk[k2];
                    while (m) {
                        const int j = (k2 << 6) + __builtin_ctzll(m);
                        m &= m - 1;
#pragma unroll
                        for (int k = 0; k < 4; ++k)
                            d2[k] += W2[(size_t)(l + 64 * k) * HID + j];
                    }
                }
            }

            // ---- LIF layer 2 ----
#pragma unroll
            for (int k = 0; k < 4; ++k) {
                m2[k] = fmaf(m2[k], leak2, d2[k]);
                const bool sp = m2[k] > thr2;
                msk[k] = __ballot(sp);
                m2[k] -= sp ? thr2 : 0.f;
            }

            // ---- acc += s2 @ W3^T + b3 ----
            float d3[4] = {b3v[0], b3v[1], b3v[2], b3v[3]};
            if (msk[0] | msk[1] | msk[2] | msk[3]) {
#pragma unroll
                for (int k2 = 0; k2 < 4; ++k2) {
                    unsigned long long m = msk[k2];
                    while (m) {
                        const int j = (k2 << 6) + __builtin_ctzll(m);
                        m &= m - 1;
#pragma unroll
                        for (int k = 0; k < 4; ++k)
                            d3[k] += W3[(size_t)(l + 64 * k) * HID + j];
                    }
                }
            }
#pragma unroll
            for (int k = 0; k < 4; ++k) acc[k] += d3[k];
        }

        if (use_precomp) {
#pragma unroll
            for (int k = 0; k < 4; ++k) X1c[k] = X1n[k];
        }
    }

    // ---- epilogue: h = acc/B ; relu(h@Wa1^T+ba1) @ Wa2^T + ba2 ----
    __shared__ float hsh[HID];
#pragma unroll
    for (int k = 0; k < 4; ++k)
        hsh[l + 64 * k] = acc[k] * (1.0f / (float)BATCH);
    __syncthreads();

    float r[4];
#pragma unroll
    for (int k = 0; k < 4; ++k) {
        const int i = l + 64 * k;
        const float4* __restrict__ wr = (const float4*)(Wa1 + (size_t)i * HID);
        const float4* __restrict__ hq = (const float4*)hsh;
        float a = ba1[i];
        for (int j4 = 0; j4 < HID / 4; ++j4) {
            float4 w = wr[j4];
            float4 h = hq[j4];
            a += w.x * h.x + w.y * h.y + w.z * h.z + w.w * h.w;
        }
        r[k] = fmaxf(a, 0.0f);
    }

    float partial = 0.f;
#pragma unroll
    for (int k = 0; k < 4; ++k)
        partial += Wa2[l + 64 * k] * r[k];
#pragma unroll
    for (int off = 32; off > 0; off >>= 1)
        partial += __shfl_down(partial, off, 64);

    if (l == 0) out[b] = partial + ba2[0];
}

// ---------------------------------------------------------------------------
extern "C" void kernel_launch(void* const* d_in, const int* in_sizes, int n_in,
                              void* d_out, int out_size, void* d_ws, size_t ws_size,
                              hipStream_t stream)
{
    const int*   text   = (const int*)  d_in[0];
    // d_in[1] = text_lengths: unused by the reference
    const float* emb    = (const float*)d_in[2];
    const float* W1     = (const float*)d_in[3];
    const float* b1     = (const float*)d_in[4];
    const float* thr1   = (const float*)d_in[5];
    const float* leak1  = (const float*)d_in[6];
    const float* W2     = (const float*)d_in[7];
    const float* b2     = (const float*)d_in[8];
    const float* thr2   = (const float*)d_in[9];
    const float* leak2  = (const float*)d_in[10];
    const float* W3     = (const float*)d_in[11];
    const float* b3     = (const float*)d_in[12];
    const float* Wa1    = (const float*)d_in[13];
    const float* ba1    = (const float*)d_in[14];
    const float* Wa2    = (const float*)d_in[15];
    const float* ba2    = (const float*)d_in[16];
    float*       out    = (float*)d_out;

    float* X1 = (float*)d_ws;
    const size_t need = (size_t)S_LEN * BATCH * HID * sizeof(float);
    const int use_precomp = (ws_size >= need) ? 1 : 0;

    if (use_precomp) {
        x1_gemm_kernel<<<(S_LEN * BATCH) / 8, 256, 0, stream>>>(text, emb, W1, b1, X1);
    }
    snn_seq_kernel<<<BATCH, 64, 0, stream>>>(
        text, emb, W1, b1, X1, use_precomp,
        W2, b2, W3, b3, thr1, leak1, thr2, leak2,
        Wa1, ba1, Wa2, ba2, out);
}

// Round 2
// 196.519 us; speedup vs baseline: 2.9177x; 2.9177x over previous
//
#include <hip/hip_runtime.h>
#include <cstdint>
#include <cstddef>

#define S_LEN  256
#define BATCH  32
#define HID    256
#define EMB    256
#define TSTEPS 10

// ---------------------------------------------------------------------------
// Kernel 1: X1_all[(s*BATCH+b)][i] = b1[i] + (tok!=0) * dot(emb[tok,:], W1[i,:])
// delta1 is timestep-invariant within a word -> precompute for all 8192 pairs.
// ---------------------------------------------------------------------------
__global__ __launch_bounds__(256) void x1_gemm_kernel(
    const int* __restrict__ text, const float* __restrict__ emb,
    const float* __restrict__ W1, const float* __restrict__ b1,
    float* __restrict__ X1)
{
    const int i  = threadIdx.x;       // neuron
    const int p0 = blockIdx.x * 8;    // (s,b) pair base

    const float4* __restrict__ wq = (const float4*)(W1 + (size_t)i * EMB);

    const float4* xq[8];
    float scale[8];
#pragma unroll
    for (int g = 0; g < 8; ++g) {
        int tok = text[p0 + g];
        tok = __builtin_amdgcn_readfirstlane(tok);   // wave-uniform
        xq[g]    = (const float4*)(emb + (size_t)tok * EMB);
        scale[g] = (tok == 0) ? 0.0f : 1.0f;         // padding_idx = 0
    }

    float acc[8] = {0.f,0.f,0.f,0.f,0.f,0.f,0.f,0.f};
#pragma unroll 4
    for (int j4 = 0; j4 < EMB / 4; ++j4) {
        float4 w = wq[j4];
#pragma unroll
        for (int g = 0; g < 8; ++g) {
            float4 x = xq[g][j4];
            acc[g] += w.x * x.x + w.y * x.y + w.z * x.z + w.w * x.w;
        }
    }

    const float bi = b1[i];
#pragma unroll
    for (int g = 0; g < 8; ++g)
        X1[(size_t)(p0 + g) * HID + i] = bi + scale[g] * acc[g];
}

// ---------------------------------------------------------------------------
// Silence analysis. LIF: m <- leak*m + delta is a convex combination of m and
// p = delta/(1-leak) when 0<=leak<1, so m stays in hull{0, all p}. Layer 1 can
// never spike (needs m > thr1 > 0) if all X1 < thr1*(1-leak1). Then layer-2
// input is exactly b2, so layer 2 is silent if all b2 < thr2*(1-leak2). Then
// acc = S*T*b3 and the recurrence is skippable. Conservative eps margins; any
// doubt -> flag nonzero -> exact fallback loop.
//
// flag bit0: param-validity / layer-2 condition failed.  bit1: X1 condition.
// ---------------------------------------------------------------------------
__global__ __launch_bounds__(256) void silent_init_kernel(
    const float* __restrict__ b2,
    const float* __restrict__ thr1p, const float* __restrict__ leak1p,
    const float* __restrict__ thr2p, const float* __restrict__ leak2p,
    int* __restrict__ flag)
{
    const float thr1  = thr1p[0],  thr2  = thr2p[0];
    const float leak1 = leak1p[0], leak2 = leak2p[0];

    __shared__ int sbad;
    if (threadIdx.x == 0) sbad = 0;
    __syncthreads();

    bool bad = false;
    if (threadIdx.x == 0) {
        bad = !(leak1 >= 0.0f && leak1 < 1.0f &&
                leak2 >= 0.0f && leak2 < 1.0f &&
                thr1 > 0.0f && thr2 > 0.0f);
    }
    // layer-2 silence: b2[i]/(1-leak2) < thr2 (with margin)
    const float c2 = thr2 * (1.0f - leak2) - 1e-4f * thr2 - 1e-6f;
    bad |= (b2[threadIdx.x] >= c2);

    const unsigned long long m = __ballot(bad);
    if ((threadIdx.x & 63) == 0 && m) atomicOr(&sbad, 1);
    __syncthreads();
    if (threadIdx.x == 0) *flag = sbad;
}

__global__ __launch_bounds__(256) void silent_check_x1_kernel(
    const float4* __restrict__ X1q,
    const float* __restrict__ thr1p, const float* __restrict__ leak1p,
    int* __restrict__ flag)
{
    const float thr1  = thr1p[0];
    const float leak1 = leak1p[0];
    const float c1 = thr1 * (1.0f - leak1) - 1e-4f * thr1 - 1e-6f;

    // 2,097,152 floats = 524,288 float4; 65,536 threads x 8 each
    int idx = blockIdx.x * 256 + threadIdx.x;
    bool bad = false;
#pragma unroll
    for (int r = 0; r < 8; ++r) {
        float4 v = X1q[idx];
        bad |= (v.x >= c1) | (v.y >= c1) | (v.z >= c1) | (v.w >= c1);
        idx += 65536;
    }
    const unsigned long long m = __ballot(bad);
    if ((threadIdx.x & 63) == 0 && m) atomicOr(flag, 2);
}

// ---------------------------------------------------------------------------
// Kernel 2: the recurrence. One wave per batch element. If flag==0 (proven
// silent), skip all 2560 steps: acc = S*T*b3 and go straight to the epilogue.
// Otherwise run the exact round-1 loop (ballot spike masks, active-column
// sums) — bit-correct for arbitrary data.
// ---------------------------------------------------------------------------
__global__ __launch_bounds__(64) void snn_seq_kernel(
    const int* __restrict__ text, const float* __restrict__ emb,
    const float* __restrict__ W1, const float* __restrict__ b1,
    const float* __restrict__ X1all, const int use_precomp,
    const int* __restrict__ flag,
    const float* __restrict__ W2, const float* __restrict__ b2,
    const float* __restrict__ W3, const float* __restrict__ b3,
    const float* __restrict__ thr1p, const float* __restrict__ leak1p,
    const float* __restrict__ thr2p, const float* __restrict__ leak2p,
    const float* __restrict__ Wa1, const float* __restrict__ ba1,
    const float* __restrict__ Wa2, const float* __restrict__ ba2,
    float* __restrict__ out)
{
    const int b = blockIdx.x;    // batch element
    const int l = threadIdx.x;   // lane

    const float thr1  = thr1p[0],  thr2  = thr2p[0];
    const float leak1 = leak1p[0], leak2 = leak2p[0];

    float b1v[4], b2v[4], b3v[4];
#pragma unroll
    for (int k = 0; k < 4; ++k) {
        b1v[k] = b1[l + 64 * k];
        b2v[k] = b2[l + 64 * k];
        b3v[k] = b3[l + 64 * k];
    }

    int f = use_precomp ? flag[0] : 1;
    f = __builtin_amdgcn_readfirstlane(f);

    float acc[4];

    if (f == 0) {
        // -------- proven silent: acc = S*T*b3 (b3 summed S*T times == S*T*b3
        // up to ulps; exact when b3 == 0) --------
#pragma unroll
        for (int k = 0; k < 4; ++k)
            acc[k] = (float)(S_LEN * TSTEPS) * b3v[k];
    } else {
        // -------- exact fallback (round-1 loop) --------
        float m1[4]  = {0.f,0.f,0.f,0.f};
        float m2[4]  = {0.f,0.f,0.f,0.f};
#pragma unroll
        for (int k = 0; k < 4; ++k) acc[k] = 0.f;

        float X1c[4] = {0.f,0.f,0.f,0.f};
        float X1n[4] = {0.f,0.f,0.f,0.f};

        if (use_precomp) {
            const size_t base0 = ((size_t)0 * BATCH + b) * HID + l;
#pragma unroll
            for (int k = 0; k < 4; ++k) X1c[k] = X1all[base0 + 64 * k];
        }

        for (int s = 0; s < S_LEN; ++s) {
            if (use_precomp) {
                if (s + 1 < S_LEN) {
                    const size_t basen = ((size_t)(s + 1) * BATCH + b) * HID + l;
#pragma unroll
                    for (int k = 0; k < 4; ++k) X1n[k] = X1all[basen + 64 * k];
                }
            } else {
                int tok = text[s * BATCH + b];
                tok = __builtin_amdgcn_readfirstlane(tok);
                const float4* __restrict__ xr = (const float4*)(emb + (size_t)tok * EMB);
                const float sc = (tok == 0) ? 0.0f : 1.0f;
#pragma unroll
                for (int k = 0; k < 4; ++k) {
                    const float4* __restrict__ wr =
                        (const float4*)(W1 + (size_t)(l + 64 * k) * EMB);
                    float a = 0.f;
                    for (int j4 = 0; j4 < EMB / 4; ++j4) {
                        float4 w = wr[j4];
                        float4 x = xr[j4];
                        a += w.x * x.x + w.y * x.y + w.z * x.z + w.w * x.w;
                    }
                    X1c[k] = b1v[k] + sc * a;
                }
            }

#pragma unroll
            for (int t = 0; t < TSTEPS; ++t) {
                unsigned long long msk[4];

#pragma unroll
                for (int k = 0; k < 4; ++k) {
                    m1[k] = fmaf(m1[k], leak1, X1c[k]);
                    const bool sp = m1[k] > thr1;
                    msk[k] = __ballot(sp);
                    m1[k] -= sp ? thr1 : 0.f;
                }

                float d2[4] = {b2v[0], b2v[1], b2v[2], b2v[3]};
                if (msk[0] | msk[1] | msk[2] | msk[3]) {
#pragma unroll
                    for (int k2 = 0; k2 < 4; ++k2) {
                        unsigned long long m = msk[k2];
                        while (m) {
                            const int j = (k2 << 6) + __builtin_ctzll(m);
                            m &= m - 1;
#pragma unroll
                            for (int k = 0; k < 4; ++k)
                                d2[k] += W2[(size_t)(l + 64 * k) * HID + j];
                        }
                    }
                }

#pragma unroll
                for (int k = 0; k < 4; ++k) {
                    m2[k] = fmaf(m2[k], leak2, d2[k]);
                    const bool sp = m2[k] > thr2;
                    msk[k] = __ballot(sp);
                    m2[k] -= sp ? thr2 : 0.f;
                }

                float d3[4] = {b3v[0], b3v[1], b3v[2], b3v[3]};
                if (msk[0] | msk[1] | msk[2] | msk[3]) {
#pragma unroll
                    for (int k2 = 0; k2 < 4; ++k2) {
                        unsigned long long m = msk[k2];
                        while (m) {
                            const int j = (k2 << 6) + __builtin_ctzll(m);
                            m &= m - 1;
#pragma unroll
                            for (int k = 0; k < 4; ++k)
                                d3[k] += W3[(size_t)(l + 64 * k) * HID + j];
                        }
                    }
                }
#pragma unroll
                for (int k = 0; k < 4; ++k) acc[k] += d3[k];
            }

            if (use_precomp) {
#pragma unroll
                for (int k = 0; k < 4; ++k) X1c[k] = X1n[k];
            }
        }
    }

    // ---- epilogue: h = acc/B ; relu(h@Wa1^T+ba1) @ Wa2^T + ba2 ----
    __shared__ float hsh[HID];
#pragma unroll
    for (int k = 0; k < 4; ++k)
        hsh[l + 64 * k] = acc[k] * (1.0f / (float)BATCH);
    __syncthreads();

    float r[4];
#pragma unroll
    for (int k = 0; k < 4; ++k) {
        const int i = l + 64 * k;
        const float4* __restrict__ wr = (const float4*)(Wa1 + (size_t)i * HID);
        const float4* __restrict__ hq = (const float4*)hsh;
        float a = ba1[i];
        for (int j4 = 0; j4 < HID / 4; ++j4) {
            float4 w = wr[j4];
            float4 h = hq[j4];
            a += w.x * h.x + w.y * h.y + w.z * h.z + w.w * h.w;
        }
        r[k] = fmaxf(a, 0.0f);
    }

    float partial = 0.f;
#pragma unroll
    for (int k = 0; k < 4; ++k)
        partial += Wa2[l + 64 * k] * r[k];
#pragma unroll
    for (int off = 32; off > 0; off >>= 1)
        partial += __shfl_down(partial, off, 64);

    if (l == 0) out[b] = partial + ba2[0];
}

// ---------------------------------------------------------------------------
extern "C" void kernel_launch(void* const* d_in, const int* in_sizes, int n_in,
                              void* d_out, int out_size, void* d_ws, size_t ws_size,
                              hipStream_t stream)
{
    const int*   text   = (const int*)  d_in[0];
    // d_in[1] = text_lengths: unused by the reference
    const float* emb    = (const float*)d_in[2];
    const float* W1     = (const float*)d_in[3];
    const float* b1     = (const float*)d_in[4];
    const float* thr1   = (const float*)d_in[5];
    const float* leak1  = (const float*)d_in[6];
    const float* W2     = (const float*)d_in[7];
    const float* b2     = (const float*)d_in[8];
    const float* thr2   = (const float*)d_in[9];
    const float* leak2  = (const float*)d_in[10];
    const float* W3     = (const float*)d_in[11];
    const float* b3     = (const float*)d_in[12];
    const float* Wa1    = (const float*)d_in[13];
    const float* ba1    = (const float*)d_in[14];
    const float* Wa2    = (const float*)d_in[15];
    const float* ba2    = (const float*)d_in[16];
    float*       out    = (float*)d_out;

    float* X1 = (float*)d_ws;
    const size_t x1_bytes = (size_t)S_LEN * BATCH * HID * sizeof(float);
    const size_t need     = x1_bytes + 64;
    const int use_precomp = (ws_size >= need) ? 1 : 0;
    int* flag = (int*)((char*)d_ws + x1_bytes);

    if (use_precomp) {
        x1_gemm_kernel<<<(S_LEN * BATCH) / 8, 256, 0, stream>>>(text, emb, W1, b1, X1);
        silent_init_kernel<<<1, 256, 0, stream>>>(b2, thr1, leak1, thr2, leak2, flag);
        silent_check_x1_kernel<<<256, 256, 0, stream>>>(
            (const float4*)X1, thr1, leak1, flag);
    }
    snn_seq_kernel<<<BATCH, 64, 0, stream>>>(
        text, emb, W1, b1, X1, use_precomp, flag,
        W2, b2, W3, b3, thr1, leak1, thr2, leak2,
        Wa1, ba1, Wa2, ba2, out);
}

// Round 3
// 158.661 us; speedup vs baseline: 3.6139x; 1.2386x over previous
//
#include <hip/hip_runtime.h>
#include <cstdint>
#include <cstddef>
#include <math.h>

#define S_LEN  256
#define BATCH  32
#define HID    256
#define EMB    256
#define TSTEPS 10

// Scratch layout (ints): [0]=bad flags, [1]=maxEmbNorm2 (float bits, atomicMax),
// [2]=maxW1Norm2 (float bits), [3]=max b1 (float bits), [4]=b3-nonzero flag.

// ---------------------------------------------------------------------------
// Kernel A: parameter validity, b2 silence condition, b3-zero test,
// max ||W1 row||^2, max b1. One block of 256 threads (thread = row/neuron).
// ---------------------------------------------------------------------------
__global__ __launch_bounds__(256) void stats_kernel(
    const float* __restrict__ W1, const float* __restrict__ b1,
    const float* __restrict__ b2, const float* __restrict__ b3,
    const float* __restrict__ thr1p, const float* __restrict__ leak1p,
    const float* __restrict__ thr2p, const float* __restrict__ leak2p,
    int* __restrict__ scratch)
{
    const int i = threadIdx.x;
    const float thr1 = thr1p[0], leak1 = leak1p[0];
    const float thr2 = thr2p[0], leak2 = leak2p[0];

    __shared__ float redW[256];
    __shared__ float redB[256];
    __shared__ int sbad, sb3;
    if (i == 0) { sbad = 0; sb3 = 0; }
    __syncthreads();

    // ||W1[i,:]||^2
    const float4* __restrict__ wr = (const float4*)(W1 + (size_t)i * EMB);
    float s = 0.f;
#pragma unroll 8
    for (int j4 = 0; j4 < EMB / 4; ++j4) {
        float4 w = wr[j4];
        s += w.x * w.x + w.y * w.y + w.z * w.z + w.w * w.w;
    }
    const float b1i = b1[i];
    redW[i] = isnan(s) ? INFINITY : s;
    redB[i] = isnan(b1i) ? INFINITY : b1i;

    bool bad = false;
    if (i == 0) {
        bad = !(leak1 >= 0.0f && leak1 < 1.0f &&
                leak2 >= 0.0f && leak2 < 1.0f &&
                thr1 > 0.0f && thr2 > 0.0f);
    }
    // layer-2 silence needs b2[i]/(1-leak2) < thr2 (conservative margin)
    const float c2 = thr2 * (1.0f - leak2) - 1e-4f * thr2 - 1e-6f;
    const float b2i = b2[i];
    bad |= !(b2i < c2);                 // catches NaN too
    const bool b3nz = (b3[i] != 0.0f) || isnan(b3[i]);

    const unsigned long long mb = __ballot(bad);
    const unsigned long long m3 = __ballot(b3nz);
    if ((i & 63) == 0) {
        if (mb) atomicOr(&sbad, 1);
        if (m3) atomicOr(&sb3, 1);
    }
    __syncthreads();
    for (int st = 128; st > 0; st >>= 1) {
        if (i < st) {
            redW[i] = fmaxf(redW[i], redW[i + st]);
            redB[i] = fmaxf(redB[i], redB[i + st]);
        }
        __syncthreads();
    }
    if (i == 0) {
        scratch[0] = sbad;
        scratch[1] = 0;                       // maxEmbNorm2 accumulator (>=0 bits)
        ((float*)scratch)[2] = redW[0];
        ((float*)scratch)[3] = redB[0];
        scratch[4] = sb3;
    }
}

// ---------------------------------------------------------------------------
// Kernel B: max ||emb[tok_p,:]||^2 over the 8192 (s,b) tokens. One wave per
// 8 tokens; lane l holds 4 floats (float4) of each row; butterfly sum; one
// atomicMax per wave. tok==0 contributes 0 (padding row is zeroed in ref).
// ---------------------------------------------------------------------------
__global__ __launch_bounds__(256) void embnorm_kernel(
    const int* __restrict__ text, const float* __restrict__ emb,
    int* __restrict__ scratch)
{
    const int l    = threadIdx.x & 63;
    const int wave = (blockIdx.x * 256 + threadIdx.x) >> 6;   // 0..1023

    float m = 0.f;
#pragma unroll
    for (int t = 0; t < 8; ++t) {
        const int tok = text[wave * 8 + t];
        const float4* __restrict__ er = (const float4*)(emb + (size_t)tok * EMB);
        float4 v = er[l];
        float s = v.x * v.x + v.y * v.y + v.z * v.z + v.w * v.w;
#pragma unroll
        for (int off = 1; off < 64; off <<= 1)
            s += __shfl_xor(s, off, 64);
        if (tok != 0) m = fmaxf(m, isnan(s) ? INFINITY : s);
    }
    if (l == 0) atomicMax(scratch + 1, __float_as_int(m));
}

// ---------------------------------------------------------------------------
// Kernel C: the recurrence. One wave per batch element.
// Silence proof (Cauchy-Schwarz): max X1 <= max(b1) + maxE*maxW. LIF with
// 0<=leak<1 keeps m <= maxX1/(1-leak), so maxX1 < thr1*(1-leak1) => layer 1
// never spikes => layer-2 input is exactly b2 => (checked in stats) layer 2
// never spikes => acc accumulates exactly b3 per step. If any condition is
// unprovable, run the exact in-kernel simulation (ballot spike masks,
// active-column sums) — bit-correct for arbitrary data.
// ---------------------------------------------------------------------------
__global__ __launch_bounds__(64) void snn_seq_kernel(
    const int* __restrict__ text, const float* __restrict__ emb,
    const float* __restrict__ W1, const float* __restrict__ b1,
    const int* __restrict__ scratch, const int force_fallback,
    const float* __restrict__ W2, const float* __restrict__ b2,
    const float* __restrict__ W3, const float* __restrict__ b3,
    const float* __restrict__ thr1p, const float* __restrict__ leak1p,
    const float* __restrict__ thr2p, const float* __restrict__ leak2p,
    const float* __restrict__ Wa1, const float* __restrict__ ba1,
    const float* __restrict__ Wa2, const float* __restrict__ ba2,
    float* __restrict__ out)
{
    const int b = blockIdx.x;    // batch element
    const int l = threadIdx.x;   // lane

    const float thr1  = thr1p[0],  thr2  = thr2p[0];
    const float leak1 = leak1p[0], leak2 = leak2p[0];

    float b1v[4], b2v[4], b3v[4];
#pragma unroll
    for (int k = 0; k < 4; ++k) {
        b1v[k] = b1[l + 64 * k];
        b2v[k] = b2[l + 64 * k];
        b3v[k] = b3[l + 64 * k];
    }

    bool silent = false;
    int  b3nz   = 1;
    if (!force_fallback) {
        const int   bad   = __builtin_amdgcn_readfirstlane(scratch[0]);
        const float maxE2 = __int_as_float(__builtin_amdgcn_readfirstlane(scratch[1]));
        const float maxW2 = __int_as_float(__builtin_amdgcn_readfirstlane(scratch[2]));
        const float maxb1 = __int_as_float(__builtin_amdgcn_readfirstlane(scratch[3]));
        b3nz = __builtin_amdgcn_readfirstlane(scratch[4]);
        const float bound = sqrtf(maxE2 * maxW2) * 1.0001f + maxb1 + 1e-6f;
        const float c1    = thr1 * (1.0f - leak1) - 1e-4f * thr1 - 1e-6f;
        silent = (bad == 0) && (bound < c1);
    }

    float acc[4];

    if (silent) {
        // layer 1 & 2 provably never spike: acc = b3 added S*T times,
        // replicated in the reference's sequential rounding order.
        if (b3nz) {
#pragma unroll
            for (int k = 0; k < 4; ++k) acc[k] = 0.f;
            for (int st = 0; st < S_LEN * TSTEPS; ++st) {
#pragma unroll
                for (int k = 0; k < 4; ++k) acc[k] += b3v[k];
            }
        } else {
#pragma unroll
            for (int k = 0; k < 4; ++k) acc[k] = 0.f;
        }
    } else {
        // -------- exact in-kernel fallback --------
        float m1[4]  = {0.f,0.f,0.f,0.f};
        float m2[4]  = {0.f,0.f,0.f,0.f};
#pragma unroll
        for (int k = 0; k < 4; ++k) acc[k] = 0.f;

        for (int s = 0; s < S_LEN; ++s) {
            float X1c[4];
            {
                int tok = text[s * BATCH + b];
                tok = __builtin_amdgcn_readfirstlane(tok);
                const float4* __restrict__ xr = (const float4*)(emb + (size_t)tok * EMB);
                const float sc = (tok == 0) ? 0.0f : 1.0f;
#pragma unroll
                for (int k = 0; k < 4; ++k) {
                    const float4* __restrict__ wr =
                        (const float4*)(W1 + (size_t)(l + 64 * k) * EMB);
                    float a = 0.f;
                    for (int j4 = 0; j4 < EMB / 4; ++j4) {
                        float4 w = wr[j4];
                        float4 x = xr[j4];
                        a += w.x * x.x + w.y * x.y + w.z * x.z + w.w * x.w;
                    }
                    X1c[k] = b1v[k] + sc * a;
                }
            }

#pragma unroll
            for (int t = 0; t < TSTEPS; ++t) {
                unsigned long long msk[4];

#pragma unroll
                for (int k = 0; k < 4; ++k) {
                    m1[k] = fmaf(m1[k], leak1, X1c[k]);
                    const bool sp = m1[k] > thr1;
                    msk[k] = __ballot(sp);
                    m1[k] -= sp ? thr1 : 0.f;
                }

                float d2[4] = {b2v[0], b2v[1], b2v[2], b2v[3]};
                if (msk[0] | msk[1] | msk[2] | msk[3]) {
#pragma unroll
                    for (int k2 = 0; k2 < 4; ++k2) {
                        unsigned long long m = msk[k2];
                        while (m) {
                            const int j = (k2 << 6) + __builtin_ctzll(m);
                            m &= m - 1;
#pragma unroll
                            for (int k = 0; k < 4; ++k)
                                d2[k] += W2[(size_t)(l + 64 * k) * HID + j];
                        }
                    }
                }

#pragma unroll
                for (int k = 0; k < 4; ++k) {
                    m2[k] = fmaf(m2[k], leak2, d2[k]);
                    const bool sp = m2[k] > thr2;
                    msk[k] = __ballot(sp);
                    m2[k] -= sp ? thr2 : 0.f;
                }

                float d3[4] = {b3v[0], b3v[1], b3v[2], b3v[3]};
                if (msk[0] | msk[1] | msk[2] | msk[3]) {
#pragma unroll
                    for (int k2 = 0; k2 < 4; ++k2) {
                        unsigned long long m = msk[k2];
                        while (m) {
                            const int j = (k2 << 6) + __builtin_ctzll(m);
                            m &= m - 1;
#pragma unroll
                            for (int k = 0; k < 4; ++k)
                                d3[k] += W3[(size_t)(l + 64 * k) * HID + j];
                        }
                    }
                }
#pragma unroll
                for (int k = 0; k < 4; ++k) acc[k] += d3[k];
            }
        }
    }

    // ---- epilogue: h = acc/B ; relu(h@Wa1^T+ba1) @ Wa2^T + ba2 ----
    __shared__ float hsh[HID];
#pragma unroll
    for (int k = 0; k < 4; ++k)
        hsh[l + 64 * k] = acc[k] * (1.0f / (float)BATCH);
    __syncthreads();

    float r[4];
#pragma unroll
    for (int k = 0; k < 4; ++k) {
        const int i = l + 64 * k;
        const float4* __restrict__ wr = (const float4*)(Wa1 + (size_t)i * HID);
        const float4* __restrict__ hq = (const float4*)hsh;
        float a = ba1[i];
        for (int j4 = 0; j4 < HID / 4; ++j4) {
            float4 w = wr[j4];
            float4 h = hq[j4];
            a += w.x * h.x + w.y * h.y + w.z * h.z + w.w * h.w;
        }
        r[k] = fmaxf(a, 0.0f);
    }

    float partial = 0.f;
#pragma unroll
    for (int k = 0; k < 4; ++k)
        partial += Wa2[l + 64 * k] * r[k];
#pragma unroll
    for (int off = 32; off > 0; off >>= 1)
        partial += __shfl_down(partial, off, 64);

    if (l == 0) out[b] = partial + ba2[0];
}

// ---------------------------------------------------------------------------
extern "C" void kernel_launch(void* const* d_in, const int* in_sizes, int n_in,
                              void* d_out, int out_size, void* d_ws, size_t ws_size,
                              hipStream_t stream)
{
    const int*   text   = (const int*)  d_in[0];
    // d_in[1] = text_lengths: unused by the reference
    const float* emb    = (const float*)d_in[2];
    const float* W1     = (const float*)d_in[3];
    const float* b1     = (const float*)d_in[4];
    const float* thr1   = (const float*)d_in[5];
    const float* leak1  = (const float*)d_in[6];
    const float* W2     = (const float*)d_in[7];
    const float* b2     = (const float*)d_in[8];
    const float* thr2   = (const float*)d_in[9];
    const float* leak2  = (const float*)d_in[10];
    const float* W3     = (const float*)d_in[11];
    const float* b3     = (const float*)d_in[12];
    const float* Wa1    = (const float*)d_in[13];
    const float* ba1    = (const float*)d_in[14];
    const float* Wa2    = (const float*)d_in[15];
    const float* ba2    = (const float*)d_in[16];
    float*       out    = (float*)d_out;

    int* scratch = (int*)d_ws;
    const int have_ws = (ws_size >= 64) ? 1 : 0;

    if (have_ws) {
        stats_kernel<<<1, 256, 0, stream>>>(W1, b1, b2, b3,
                                            thr1, leak1, thr2, leak2, scratch);
        embnorm_kernel<<<256, 256, 0, stream>>>(text, emb, scratch);
    }
    snn_seq_kernel<<<BATCH, 64, 0, stream>>>(
        text, emb, W1, b1, scratch, have_ws ? 0 : 1,
        W2, b2, W3, b3, thr1, leak1, thr2, leak2,
        Wa1, ba1, Wa2, ba2, out);
}